// Round 3
// baseline (79.369 us; speedup 1.0000x reference)
//
#include <hip/hip_runtime.h>

// CARAFE: x [4,256,64,64] f32, kernel [4,25,128,128] f32 -> out [4,256,128,128] f32
// out[b,c,2h+p,2w+q] = sum_{ki,kj} x[b,c,h+ki-2,w+kj-2] * kern[b,ki*5+kj,2h+p,2w+q]

#define BN   4
#define CN   256
#define HN   64
#define WN   64
#define KS   5
#define K2   25
#define OHN  128
#define OWN  128
#define PADN 2

#define XCOLS 68      // WN + 2*PADN
#define XPADC 36      // padded channel stride (multiple of 4 for b128 alignment)
#define NCHB  32      // channels per block

__global__ __launch_bounds__(256, 2)
void carafe_kernel(const float* __restrict__ x,
                   const float* __restrict__ kern,
                   float* __restrict__ out) {
    __shared__ float wt[K2 * 2 * OWN];            // 6400 f32 = 25.6 KB
    __shared__ float xs[KS * XCOLS * XPADC];      // 12240 f32 = 48.96 KB

    const int bid = blockIdx.x;
    const int cc  = bid & 7;           // channel chunk (8 chunks of 32)
    const int h   = (bid >> 3) & 63;   // input row
    const int b   = bid >> 9;          // batch
    const int tid = threadIdx.x;

    // ---- stage weights for output rows {2h, 2h+1}, all 25 taps, all 128 ow ----
    const float* kbase = kern + (size_t)b * K2 * OHN * OWN + (size_t)(2 * h) * OWN;
    for (int idx = tid; idx < K2 * 2 * OWN; idx += 256) {
        const int k  = idx >> 8;          // tap
        const int r  = idx & 255;
        const int p  = r >> 7;            // sub-row 0/1
        const int ow = r & 127;
        wt[idx] = kbase[(size_t)k * OHN * OWN + p * OWN + ow];   // coalesced in ow
    }

    // ---- stage x tile: 32 channels x rows [h-2,h+2] x cols [-2,65] (zero-padded) ----
    const int c0 = cc * NCHB;
    const float* xbase = x + (size_t)(b * CN + c0) * HN * WN;
    for (int idx = tid; idx < KS * XCOLS * NCHB; idx += 256) {
        const int col = idx % XCOLS;          // fastest -> coalesced global read
        const int t   = idx / XCOLS;
        const int row = t % KS;
        const int ch  = t / KS;
        const int gr  = h + row - PADN;
        const int gc  = col - PADN;
        float v = 0.0f;
        if ((unsigned)gr < HN && (unsigned)gc < WN)
            v = xbase[(size_t)ch * HN * WN + gr * WN + gc];
        xs[(row * XCOLS + col) * XPADC + ch] = v;
    }
    __syncthreads();

    const int w  = tid & 63;    // input column
    const int cg = tid >> 6;    // 8-channel group within the 32-channel chunk

    float acc[4][8];            // [p*2+q][ch]
#pragma unroll
    for (int i = 0; i < 4; ++i)
#pragma unroll
        for (int j = 0; j < 8; ++j) acc[i][j] = 0.0f;

#pragma unroll
    for (int ki = 0; ki < KS; ++ki) {
#pragma unroll
        for (int kj = 0; kj < KS; ++kj) {
            const int k = ki * KS + kj;
            const int xb = (ki * XCOLS + (w + kj)) * XPADC + cg * 8;
            const float4 xlo = *(const float4*)&xs[xb];       // ds_read_b128
            const float4 xhi = *(const float4*)&xs[xb + 4];
            const float2 w0 = *(const float2*)&wt[k * 256 + 2 * w];        // p=0, q=0..1
            const float2 w1 = *(const float2*)&wt[k * 256 + 128 + 2 * w];  // p=1, q=0..1
            const float xv[8] = {xlo.x, xlo.y, xlo.z, xlo.w,
                                 xhi.x, xhi.y, xhi.z, xhi.w};
#pragma unroll
            for (int ch = 0; ch < 8; ++ch) {
                acc[0][ch] += w0.x * xv[ch];
                acc[1][ch] += w0.y * xv[ch];
                acc[2][ch] += w1.x * xv[ch];
                acc[3][ch] += w1.y * xv[ch];
            }
        }
    }

    // ---- write: float2 per (ch,p) -> lanes cover contiguous 512B, fully coalesced ----
    float* obase = out + ((size_t)(b * CN + c0 + cg * 8) * OHN + 2 * h) * OWN + 2 * w;
#pragma unroll
    for (int ch = 0; ch < 8; ++ch) {
#pragma unroll
        for (int p = 0; p < 2; ++p) {
            float2 v;
            v.x = acc[p * 2 + 0][ch];
            v.y = acc[p * 2 + 1][ch];
            *(float2*)(obase + (size_t)ch * OHN * OWN + p * OWN) = v;
        }
    }
}

extern "C" void kernel_launch(void* const* d_in, const int* in_sizes, int n_in,
                              void* d_out, int out_size, void* d_ws, size_t ws_size,
                              hipStream_t stream) {
    const float* x    = (const float*)d_in[0];
    const float* kern = (const float*)d_in[1];
    float* out        = (float*)d_out;
    // grid: b(4) * h(64) * cc(8) = 2048 blocks
    carafe_kernel<<<dim3(BN * HN * 8), dim3(256), 0, stream>>>(x, kern, out);
}